// Round 10
// baseline (67.382 us; speedup 1.0000x reference)
//
#include <hip/hip_runtime.h>
#include <math.h>

#define N_S 1024
#define XD  768
#define LOW 300
#define KP  320     // f16 k-padding
#define KP2 160     // u32 (h2) per row

typedef _Float16 h2  __attribute__((ext_vector_type(2)));
typedef __fp16   g2  __attribute__((ext_vector_type(2)));
typedef _Float16 v8h __attribute__((ext_vector_type(8)));
typedef float    f4  __attribute__((ext_vector_type(4)));

union U32H2 { unsigned int u; h2 h; };
__device__ inline h2 u2h(unsigned int v){ U32H2 t; t.u = v; return t.h; }
__device__ inline unsigned int pk(float a, float b){
    g2 t = __builtin_amdgcn_cvt_pkrtz(a, b);
    return __builtin_bit_cast(unsigned int, t);
}
union U4V8 { uint4 u; v8h v; };

// ---------------------------------------------------------------------------
// Kernel 1: projection GEMM via MFMA f16. 320 jobs of 32-row x 64-kcol.
//   job < 160 : hx[j][k] = sum_m x[j,m]*W1[m,k]
//   job >=160 : hy[i][k] = sum_m y[i,m]*W1[768+m,k] + b1[k]
// 512 thr = 8 waves (2M x 4N quadrants), K-step 64, double-buffered.
// 320 blocks x 8 waves -> 10 waves/CU (2.5/SIMD) for latency hiding.
// Block 0 also zeroes the pair-completion counter (stream-ordered).
// ---------------------------------------------------------------------------
__global__ __launch_bounds__(512)
void gemm_h(const float* __restrict__ x, const float* __restrict__ y,
            const float* __restrict__ W1, const float* __restrict__ b1g,
            unsigned int* __restrict__ hx_h, unsigned int* __restrict__ hy_h,
            unsigned int* __restrict__ cnt)
{
    __shared__ unsigned int As[2][32][34];
    __shared__ unsigned int Bs[2][64][34];

    const int tid = threadIdx.x;
    const int job = blockIdx.x;
    if (job == 0 && tid == 0) cnt[0] = 0;

    const int which = job >= 160;
    const int t = which ? job - 160 : job;
    const int n0 = (t % 5) * 64;
    const int r0 = (t / 5) * 32;
    const float* A = which ? y : x;
    const float* W = W1 + (size_t)which * XD * LOW;
    _Float16* outh = (_Float16*)(which ? hy_h : hx_h);

    const int w = tid >> 6, l = tid & 63;
    const int wm = w >> 2, wn = w & 3;         // 2M x 4N
    const int lr = l & 15, lg = l >> 4;

    const int arow = tid >> 4, aq = tid & 15;  // A staging: 32 rows x 16 f4-groups
    const int bn = tid & 63, bms = tid >> 6;   // B staging: 64 ncols x 8 m-groups
    const bool bin = (n0 + bn) < LOW;

    f4 acc = {};
    float4 a0; float bw[8];
    a0 = *(const float4*)&A[(size_t)(r0 + arow) * XD + aq * 4];
    #pragma unroll
    for (int s = 0; s < 8; ++s)
        bw[s] = bin ? W[(size_t)(bms * 8 + s) * LOW + n0 + bn] : 0.f;

    const int NC = XD / 64;                    // 12
    for (int c = 0; c < NC; ++c) {
        const int buf = c & 1;
        *(uint2*)&As[buf][arow][aq * 2] = make_uint2(pk(a0.x, a0.y), pk(a0.z, a0.w));
        *(uint4*)&Bs[buf][bn][bms * 4] =
            uint4{ pk(bw[0],bw[1]), pk(bw[2],bw[3]), pk(bw[4],bw[5]), pk(bw[6],bw[7]) };
        __syncthreads();
        if (c + 1 < NC) {
            const int kb = (c + 1) * 64;
            a0 = *(const float4*)&A[(size_t)(r0 + arow) * XD + kb + aq * 4];
            #pragma unroll
            for (int s = 0; s < 8; ++s)
                bw[s] = bin ? W[(size_t)(kb + bms * 8 + s) * LOW + n0 + bn] : 0.f;
        }
        #pragma unroll
        for (int ks = 0; ks < 2; ++ks) {
            const int ko = ks * 16 + lg * 4;
            U4V8 af; af.u = *(const uint4*)&As[buf][wm * 16 + lr][ko];
            U4V8 bf; bf.u = *(const uint4*)&Bs[buf][wn * 16 + lr][ko];
            acc = __builtin_amdgcn_mfma_f32_16x16x32_f16(af.v, bf.v, acc, 0, 0, 0);
        }
    }

    // D: col = l&15, row = 4*(l>>4)+r  (m89-verified)
    const int col = n0 + wn * 16 + lr;
    const float b1v = (which && col < LOW) ? b1g[col] : 0.f;
    #pragma unroll
    for (int r = 0; r < 4; ++r) {
        const int row = r0 + wm * 16 + lg * 4 + r;
        outh[(size_t)row * KP + col] = (_Float16)(acc[r] + b1v);
    }
}

// ---------------------------------------------------------------------------
// Kernel 2: pairwise critic (r9-verified core) + fused final reduction.
//   s[i][j] = sum_k relu(hy[i,k]+hx[j,k])*w2[k] + b2
//   part[i][jb] = sum_j e^s;  diag[i] = softplus(s[i][i])
// Tile 32(i) x 64(j), 256 thr, 512 blocks. 4i x 4j x half-k per thread,
// whole K staged once (one barrier); k-halves combined via shfl_xor(16).
// Last finishing block (atomic counter) computes lse + mean -> out.
// ---------------------------------------------------------------------------
__global__ __launch_bounds__(256)
void pair_kernel(const unsigned int* __restrict__ hx_h, const unsigned int* __restrict__ hy_h,
                 const float* __restrict__ W2, const float* __restrict__ b2,
                 float* __restrict__ part, float* __restrict__ diag,
                 unsigned int* __restrict__ cnt, float* __restrict__ out)
{
    const int jb = blockIdx.x & 15, ib = blockIdx.x >> 4;
    const int j0 = jb * 64, i0 = ib * 32;

    __shared__ unsigned int Hy[160][34];   // [kk][i]
    __shared__ unsigned int Hx[160][66];   // [kk][j]
    __shared__ unsigned int w2s[KP2];
    __shared__ unsigned int lastFlag;

    const int tid = threadIdx.x;

    // ---- stage Hy: transpose [i][kk] -> [kk][i] ----
    {
        const int r = tid >> 3, q = tid & 7;
        const unsigned int* src = &hy_h[(size_t)(i0 + r) * KP2];
        #pragma unroll
        for (int e = 0; e < 5; ++e) {
            const int k4 = q + 8 * e;
            uint4 v = *(const uint4*)&src[k4 * 4];
            Hy[k4*4+0][r] = v.x; Hy[k4*4+1][r] = v.y;
            Hy[k4*4+2][r] = v.z; Hy[k4*4+3][r] = v.w;
        }
    }
    // ---- stage Hx ----
    {
        const int r = tid >> 2, q = tid & 3;
        const unsigned int* src = &hx_h[(size_t)(j0 + r) * KP2];
        #pragma unroll
        for (int e = 0; e < 10; ++e) {
            const int k4 = q + 4 * e;
            uint4 v = *(const uint4*)&src[k4 * 4];
            Hx[k4*4+0][r] = v.x; Hx[k4*4+1][r] = v.y;
            Hx[k4*4+2][r] = v.z; Hx[k4*4+3][r] = v.w;
        }
    }
    if (tid < KP2) {
        int k = tid * 2;
        float w0 = (k < LOW) ? W2[k] : 0.f;
        float w1 = (k + 1 < LOW) ? W2[k + 1] : 0.f;
        w2s[tid] = pk(w0, w1);
    }
    __syncthreads();

    const int tx = tid & 15;           // j = j0 + tx*4 + q
    const int kh = (tid >> 4) & 1;     // k-half
    const int iy = tid >> 5;           // i = i0 + iy*4 + r

    float acc[4][4] = {};
    const h2 hz = h2{(_Float16)0.f, (_Float16)0.f};
    const int kbase = kh * 80;

    #pragma unroll 4
    for (int kki = 0; kki < 80; ++kki) {
        const int kk = kbase + kki;
        const uint4 ya = *(const uint4*)&Hy[kk][iy * 4];
        const uint4 xb = *(const uint4*)&Hx[kk][tx * 4];
        const h2 w = u2h(w2s[kk]);
        const unsigned int yar[4] = {ya.x, ya.y, ya.z, ya.w};
        const unsigned int xbr[4] = {xb.x, xb.y, xb.z, xb.w};
        #pragma unroll
        for (int r = 0; r < 4; ++r) {
            const h2 a = u2h(yar[r]);
            #pragma unroll
            for (int q = 0; q < 4; ++q) {
                h2 z = __builtin_elementwise_max(a + u2h(xbr[q]), hz);
                acc[r][q] = __builtin_amdgcn_fdot2(z, w, acc[r][q], false);
            }
        }
    }

    #pragma unroll
    for (int r = 0; r < 4; ++r)
        #pragma unroll
        for (int q = 0; q < 4; ++q)
            acc[r][q] += __shfl_xor(acc[r][q], 16, 64);

    const float b2v = b2[0];
    #pragma unroll
    for (int r = 0; r < 4; ++r) {
        const int row = i0 + iy * 4 + r;
        float es = 0.f;
        #pragma unroll
        for (int q = 0; q < 4; ++q) {
            const float s = acc[r][q] + b2v;
            es += __expf(s);
            const int col = j0 + tx * 4 + q;
            if (col == row)
                diag[row] = fmaxf(s, 0.f) + __logf(1.f + __expf(-fabsf(s)));
        }
        #pragma unroll
        for (int o = 1; o <= 8; o <<= 1) es += __shfl_xor(es, o, 64);
        if ((tid & 31) == 0) part[(size_t)row * 16 + jb] = es;
    }

    // ---- last-block-done: final lse + mean ----
    __threadfence();                       // release part/diag
    if (tid == 0) lastFlag = (atomicAdd(cnt, 1u) == 511u);
    __syncthreads();
    if (!lastFlag) return;
    __threadfence();                       // acquire all blocks' part/diag

    __shared__ float ssum[4];
    float csum = 0.f;
    #pragma unroll
    for (int g = 0; g < 4; ++g) {
        const int row = g * 256 + tid;
        const float4* p = (const float4*)(part + (size_t)row * 16);
        float s = 0.f;
        #pragma unroll
        for (int q = 0; q < 4; ++q) {
            float4 v = p[q];
            s += (v.x + v.y) + (v.z + v.w);
        }
        csum += diag[row] - __logf((float)N_S + s);   // exp(softplus)=1+e^s
    }
    #pragma unroll
    for (int o = 32; o > 0; o >>= 1) csum += __shfl_xor(csum, o, 64);
    if ((tid & 63) == 0) ssum[tid >> 6] = csum;
    __syncthreads();
    if (tid == 0)
        out[0] = (ssum[0] + ssum[1] + ssum[2] + ssum[3]) * (1.0f / N_S)
               - logf((float)N_S);
}

// ---------------------------------------------------------------------------
extern "C" void kernel_launch(void* const* d_in, const int* in_sizes, int n_in,
                              void* d_out, int out_size, void* d_ws, size_t ws_size,
                              hipStream_t stream)
{
    const float* x  = (const float*)d_in[0];
    const float* y  = (const float*)d_in[1];
    const float* W1 = (const float*)d_in[2];
    const float* b1 = (const float*)d_in[3];
    const float* W2 = (const float*)d_in[4];
    const float* b2 = (const float*)d_in[5];
    float* outp = (float*)d_out;

    unsigned int* hx_h = (unsigned int*)d_ws;             // N_S*KP2 u32
    unsigned int* hy_h = hx_h + (size_t)N_S * KP2;        // N_S*KP2 u32
    float* part = (float*)(hy_h + (size_t)N_S * KP2);     // N_S*16 f32
    float* diag = part + (size_t)N_S * 16;                // N_S f32
    unsigned int* cnt = (unsigned int*)(diag + N_S);      // 1 u32

    gemm_h<<<320, 512, 0, stream>>>(x, y, W1, b1, hx_h, hy_h, cnt);

    pair_kernel<<<512, 256, 0, stream>>>(hx_h, hy_h, W2, b2, part, diag,
                                         cnt, outp);
}

// Round 11
// 43.605 us; speedup vs baseline: 1.5453x; 1.5453x over previous
//
#include <hip/hip_runtime.h>
#include <math.h>

#define N_S 1024
#define XD  768
#define LOW 300
#define KP  320     // f16 k-padding
#define KP2 160     // u32 (h2) per row

typedef _Float16 h2  __attribute__((ext_vector_type(2)));
typedef __fp16   g2  __attribute__((ext_vector_type(2)));
typedef _Float16 v8h __attribute__((ext_vector_type(8)));
typedef float    f4  __attribute__((ext_vector_type(4)));

union U32H2 { unsigned int u; h2 h; };
__device__ inline h2 u2h(unsigned int v){ U32H2 t; t.u = v; return t.h; }
__device__ inline unsigned int pk(float a, float b){
    g2 t = __builtin_amdgcn_cvt_pkrtz(a, b);
    return __builtin_bit_cast(unsigned int, t);
}
union U4V8 { uint4 u; v8h v; };

// ---------------------------------------------------------------------------
// Kernel 1: projection GEMM via MFMA f16. 320 jobs of 32-row x 64-kcol.
//   job < 160 : hx[j][k] = sum_m x[j,m]*W1[m,k]
//   job >=160 : hy[i][k] = sum_m y[i,m]*W1[768+m,k] + b1[k]
// 512 thr = 8 waves (2M x 4N), K-step 64, double-buffered, stride 36
// (16B-aligned rows -> true ds_read_b128 fragments).
// ---------------------------------------------------------------------------
__global__ __launch_bounds__(512)
void gemm_h(const float* __restrict__ x, const float* __restrict__ y,
            const float* __restrict__ W1, const float* __restrict__ b1g,
            unsigned int* __restrict__ hx_h, unsigned int* __restrict__ hy_h)
{
    __shared__ unsigned int As[2][32][36];
    __shared__ unsigned int Bs[2][64][36];

    const int tid = threadIdx.x;
    const int job = blockIdx.x;
    const int which = job >= 160;
    const int t = which ? job - 160 : job;
    const int n0 = (t % 5) * 64;
    const int r0 = (t / 5) * 32;
    const float* A = which ? y : x;
    const float* W = W1 + (size_t)which * XD * LOW;
    _Float16* outh = (_Float16*)(which ? hy_h : hx_h);

    const int w = tid >> 6, l = tid & 63;
    const int wm = w >> 2, wn = w & 3;         // 2M x 4N
    const int lr = l & 15, lg = l >> 4;

    const int arow = tid >> 4, aq = tid & 15;  // A staging: 32 rows x 16 f4
    const int bn = tid & 63, bms = tid >> 6;   // B staging: 64 ncols x 8 m-grp
    const bool bin = (n0 + bn) < LOW;

    f4 acc = {};
    float4 a0; float bw[8];
    a0 = *(const float4*)&A[(size_t)(r0 + arow) * XD + aq * 4];
    #pragma unroll
    for (int s = 0; s < 8; ++s)
        bw[s] = bin ? W[(size_t)(bms * 8 + s) * LOW + n0 + bn] : 0.f;

    const int NC = XD / 64;                    // 12
    for (int c = 0; c < NC; ++c) {
        const int buf = c & 1;
        *(uint2*)&As[buf][arow][aq * 2] = make_uint2(pk(a0.x, a0.y), pk(a0.z, a0.w));
        *(uint4*)&Bs[buf][bn][bms * 4] =
            uint4{ pk(bw[0],bw[1]), pk(bw[2],bw[3]), pk(bw[4],bw[5]), pk(bw[6],bw[7]) };
        __syncthreads();
        if (c + 1 < NC) {
            const int kb = (c + 1) * 64;
            a0 = *(const float4*)&A[(size_t)(r0 + arow) * XD + kb + aq * 4];
            #pragma unroll
            for (int s = 0; s < 8; ++s)
                bw[s] = bin ? W[(size_t)(kb + bms * 8 + s) * LOW + n0 + bn] : 0.f;
        }
        #pragma unroll
        for (int ks = 0; ks < 2; ++ks) {
            const int ko = ks * 16 + lg * 4;
            U4V8 af; af.u = *(const uint4*)&As[buf][wm * 16 + lr][ko];
            U4V8 bf; bf.u = *(const uint4*)&Bs[buf][wn * 16 + lr][ko];
            acc = __builtin_amdgcn_mfma_f32_16x16x32_f16(af.v, bf.v, acc, 0, 0, 0);
        }
    }

    // D: col = l&15, row = 4*(l>>4)+r  (m89-verified)
    const int col = n0 + wn * 16 + lr;
    const float b1v = (which && col < LOW) ? b1g[col] : 0.f;
    #pragma unroll
    for (int r = 0; r < 4; ++r) {
        const int row = r0 + wm * 16 + lg * 4 + r;
        outh[(size_t)row * KP + col] = (_Float16)(acc[r] + b1v);
    }
}

// ---------------------------------------------------------------------------
// Kernel 2: pairwise critic, 8i x 8j x 8-way-interleaved-k per thread.
//   s[i][j] = sum_k relu(hy[i,k]+hx[j,k])*w2[k] + b2
//   part[i][jb] = sum_j e^s;   diag[i] = softplus(s[i][i])
// Tile 32(i) x 64(j), 256 thr, 512 blocks (2/CU, 8 waves/CU).
// Lane map: tx=tid&7 (8 j), kh=(tid>>3)&7 (k-slice: kk=8t+kh), iy=tid>>6
// (wave -> 8 i). Whole K staged once (67 KB LDS, strides 36/68: 16B rows,
// consecutive-kk lanes spread banks). 5 LDS reads per 192 VALU; k-slices
// combined with 3 in-wave shfl_xor.
// ---------------------------------------------------------------------------
__global__ __launch_bounds__(256)
void pair_kernel(const unsigned int* __restrict__ hx_h, const unsigned int* __restrict__ hy_h,
                 const float* __restrict__ W2, const float* __restrict__ b2,
                 float* __restrict__ part, float* __restrict__ diag)
{
    const int jb = blockIdx.x, ib = blockIdx.y;
    const int j0 = jb * 64, i0 = ib * 32;

    __shared__ unsigned int Hy[160][36];   // [kk][i]
    __shared__ unsigned int Hx[160][68];   // [kk][j]
    __shared__ unsigned int w2s[KP2];

    const int tid = threadIdx.x;

    // ---- stage Hy: transpose [i][kk] -> [kk][i] ----
    {
        const int r = tid >> 3, q = tid & 7;
        const unsigned int* src = &hy_h[(size_t)(i0 + r) * KP2];
        #pragma unroll
        for (int e = 0; e < 5; ++e) {
            const int k4 = q + 8 * e;
            uint4 v = *(const uint4*)&src[k4 * 4];
            Hy[k4*4+0][r] = v.x; Hy[k4*4+1][r] = v.y;
            Hy[k4*4+2][r] = v.z; Hy[k4*4+3][r] = v.w;
        }
    }
    // ---- stage Hx ----
    {
        const int r = tid >> 2, q = tid & 3;
        const unsigned int* src = &hx_h[(size_t)(j0 + r) * KP2];
        #pragma unroll
        for (int e = 0; e < 10; ++e) {
            const int k4 = q + 4 * e;
            uint4 v = *(const uint4*)&src[k4 * 4];
            Hx[k4*4+0][r] = v.x; Hx[k4*4+1][r] = v.y;
            Hx[k4*4+2][r] = v.z; Hx[k4*4+3][r] = v.w;
        }
    }
    if (tid < KP2) {
        int k = tid * 2;
        float w0 = (k < LOW) ? W2[k] : 0.f;
        float w1 = (k + 1 < LOW) ? W2[k + 1] : 0.f;
        w2s[tid] = pk(w0, w1);
    }
    __syncthreads();

    const int tx = tid & 7;            // j = j0 + tx*8 + q
    const int kh = (tid >> 3) & 7;     // k-slice: kk = 8t + kh
    const int iy = tid >> 6;           // wave: i = i0 + iy*8 + r

    float acc[8][8] = {};              // [r][q], 64 VGPR
    const h2 hz = h2{(_Float16)0.f, (_Float16)0.f};

    const unsigned int* HyK = &Hy[kh][iy * 8];
    const unsigned int* HxK = &Hx[kh][tx * 8];

    #pragma unroll 4
    for (int t = 0; t < 20; ++t) {
        const uint4 ya0 = *(const uint4*)(HyK + 8 * t * 36);
        const uint4 ya1 = *(const uint4*)(HyK + 8 * t * 36 + 4);
        const uint4 xb0 = *(const uint4*)(HxK + 8 * t * 68);
        const uint4 xb1 = *(const uint4*)(HxK + 8 * t * 68 + 4);
        const h2 w = u2h(w2s[8 * t + kh]);
        const unsigned int yar[8] = {ya0.x, ya0.y, ya0.z, ya0.w,
                                     ya1.x, ya1.y, ya1.z, ya1.w};
        const unsigned int xbr[8] = {xb0.x, xb0.y, xb0.z, xb0.w,
                                     xb1.x, xb1.y, xb1.z, xb1.w};
        #pragma unroll
        for (int r = 0; r < 8; ++r) {
            const h2 a = u2h(yar[r]);
            #pragma unroll
            for (int q = 0; q < 8; ++q) {
                h2 z = __builtin_elementwise_max(a + u2h(xbr[q]), hz);
                acc[r][q] = __builtin_amdgcn_fdot2(z, w, acc[r][q], false);
            }
        }
    }

    // combine 8 k-slices (kh = tid bits 3..5): in-wave butterfly
    #pragma unroll
    for (int r = 0; r < 8; ++r)
        #pragma unroll
        for (int q = 0; q < 8; ++q) {
            float v = acc[r][q];
            v += __shfl_xor(v, 8, 64);
            v += __shfl_xor(v, 16, 64);
            v += __shfl_xor(v, 32, 64);
            acc[r][q] = v;
        }

    const float b2v = b2[0];
    #pragma unroll
    for (int r = 0; r < 8; ++r) {
        const int row = i0 + iy * 8 + r;
        float es = 0.f;
        #pragma unroll
        for (int q = 0; q < 8; ++q) {
            const float s = acc[r][q] + b2v;
            es += __expf(s);                       // exp(softplus) = 1+e^s
            const int col = j0 + tx * 8 + q;
            if (col == row)
                diag[row] = fmaxf(s, 0.f) + __logf(1.f + __expf(-fabsf(s)));
        }
        es += __shfl_xor(es, 1, 64);               // reduce over tx (bits 0..2)
        es += __shfl_xor(es, 2, 64);
        es += __shfl_xor(es, 4, 64);
        if ((tid & 63) == 0) part[(size_t)row * 16 + jb] = es;
    }
}

// ---------------------------------------------------------------------------
// Kernel 3: per-row lse from 16 partials + global mean. One 256-thr block.
//   lse_i = log(N + sum_jb part[i][jb])
// ---------------------------------------------------------------------------
__global__ __launch_bounds__(256)
void lse_final(const float* __restrict__ part, const float* __restrict__ diag,
               float* __restrict__ out)
{
    __shared__ float ssum[4];
    const int tid = threadIdx.x;
    float csum = 0.f;
    #pragma unroll
    for (int g = 0; g < 4; ++g) {
        const int row = g * 256 + tid;
        const float4* p = (const float4*)(part + (size_t)row * 16);
        float s = 0.f;
        #pragma unroll
        for (int q = 0; q < 4; ++q) {
            float4 v = p[q];
            s += (v.x + v.y) + (v.z + v.w);
        }
        csum += diag[row] - __logf((float)N_S + s);
    }
    #pragma unroll
    for (int o = 32; o > 0; o >>= 1) csum += __shfl_xor(csum, o, 64);
    if ((tid & 63) == 0) ssum[tid >> 6] = csum;
    __syncthreads();
    if (tid == 0)
        out[0] = (ssum[0] + ssum[1] + ssum[2] + ssum[3]) * (1.0f / N_S)
               - logf((float)N_S);
}

// ---------------------------------------------------------------------------
extern "C" void kernel_launch(void* const* d_in, const int* in_sizes, int n_in,
                              void* d_out, int out_size, void* d_ws, size_t ws_size,
                              hipStream_t stream)
{
    const float* x  = (const float*)d_in[0];
    const float* y  = (const float*)d_in[1];
    const float* W1 = (const float*)d_in[2];
    const float* b1 = (const float*)d_in[3];
    const float* W2 = (const float*)d_in[4];
    const float* b2 = (const float*)d_in[5];
    float* outp = (float*)d_out;

    unsigned int* hx_h = (unsigned int*)d_ws;             // N_S*KP2 u32
    unsigned int* hy_h = hx_h + (size_t)N_S * KP2;        // N_S*KP2 u32
    float* part = (float*)(hy_h + (size_t)N_S * KP2);     // N_S*16 f32
    float* diag = part + (size_t)N_S * 16;                // N_S f32

    gemm_h<<<320, 512, 0, stream>>>(x, y, W1, b1, hx_h, hy_h);

    dim3 g2(16, 32);                      // j-tiles, i-tiles
    pair_kernel<<<g2, 256, 0, stream>>>(hx_h, hy_h, W2, b2, part, diag);

    lse_final<<<1, 256, 0, stream>>>(part, diag, outp);
}

// Round 12
// 41.292 us; speedup vs baseline: 1.6319x; 1.0560x over previous
//
#include <hip/hip_runtime.h>
#include <math.h>

#define N_S 1024
#define XD  768
#define LOW 300
#define KP  320     // f16 k-padding
#define KP2 160     // u32 (h2) per row

typedef _Float16 h2  __attribute__((ext_vector_type(2)));
typedef __fp16   g2  __attribute__((ext_vector_type(2)));
typedef _Float16 v8h __attribute__((ext_vector_type(8)));
typedef float    f4  __attribute__((ext_vector_type(4)));

union U32H2 { unsigned int u; h2 h; };
__device__ inline h2 u2h(unsigned int v){ U32H2 t; t.u = v; return t.h; }
__device__ inline unsigned int pk(float a, float b){
    g2 t = __builtin_amdgcn_cvt_pkrtz(a, b);
    return __builtin_bit_cast(unsigned int, t);
}
union U4V8 { uint4 u; v8h v; };

// ---------------------------------------------------------------------------
// Kernel 1: projection GEMM via MFMA f16 (r11-verified). 320 jobs 32r x 64k.
// Also zeroes partsum[1024] and cnt (visible to kernel 2 via stream order).
// ---------------------------------------------------------------------------
__global__ __launch_bounds__(512)
void gemm_h(const float* __restrict__ x, const float* __restrict__ y,
            const float* __restrict__ W1, const float* __restrict__ b1g,
            unsigned int* __restrict__ hx_h, unsigned int* __restrict__ hy_h,
            float* __restrict__ partsum, unsigned int* __restrict__ cnt)
{
    __shared__ unsigned int As[2][32][36];
    __shared__ unsigned int Bs[2][64][36];

    const int tid = threadIdx.x;
    const int job = blockIdx.x;
    if (job < 256 && tid < 4) partsum[job * 4 + tid] = 0.f;
    if (job == 0 && tid == 4) cnt[0] = 0u;

    const int which = job >= 160;
    const int t = which ? job - 160 : job;
    const int n0 = (t % 5) * 64;
    const int r0 = (t / 5) * 32;
    const float* A = which ? y : x;
    const float* W = W1 + (size_t)which * XD * LOW;
    _Float16* outh = (_Float16*)(which ? hy_h : hx_h);

    const int w = tid >> 6, l = tid & 63;
    const int wm = w >> 2, wn = w & 3;         // 2M x 4N
    const int lr = l & 15, lg = l >> 4;

    const int arow = tid >> 4, aq = tid & 15;  // A staging: 32 rows x 16 f4
    const int bn = tid & 63, bms = tid >> 6;   // B staging: 64 ncols x 8 m-grp
    const bool bin = (n0 + bn) < LOW;

    f4 acc = {};
    float4 a0; float bw[8];
    a0 = *(const float4*)&A[(size_t)(r0 + arow) * XD + aq * 4];
    #pragma unroll
    for (int s = 0; s < 8; ++s)
        bw[s] = bin ? W[(size_t)(bms * 8 + s) * LOW + n0 + bn] : 0.f;

    const int NC = XD / 64;                    // 12
    for (int c = 0; c < NC; ++c) {
        const int buf = c & 1;
        *(uint2*)&As[buf][arow][aq * 2] = make_uint2(pk(a0.x, a0.y), pk(a0.z, a0.w));
        *(uint4*)&Bs[buf][bn][bms * 4] =
            uint4{ pk(bw[0],bw[1]), pk(bw[2],bw[3]), pk(bw[4],bw[5]), pk(bw[6],bw[7]) };
        __syncthreads();
        if (c + 1 < NC) {
            const int kb = (c + 1) * 64;
            a0 = *(const float4*)&A[(size_t)(r0 + arow) * XD + kb + aq * 4];
            #pragma unroll
            for (int s = 0; s < 8; ++s)
                bw[s] = bin ? W[(size_t)(kb + bms * 8 + s) * LOW + n0 + bn] : 0.f;
        }
        #pragma unroll
        for (int ks = 0; ks < 2; ++ks) {
            const int ko = ks * 16 + lg * 4;
            U4V8 af; af.u = *(const uint4*)&As[buf][wm * 16 + lr][ko];
            U4V8 bf; bf.u = *(const uint4*)&Bs[buf][wn * 16 + lr][ko];
            acc = __builtin_amdgcn_mfma_f32_16x16x32_f16(af.v, bf.v, acc, 0, 0, 0);
        }
    }

    // D: col = l&15, row = 4*(l>>4)+r  (m89-verified)
    const int col = n0 + wn * 16 + lr;
    const float b1v = (which && col < LOW) ? b1g[col] : 0.f;
    #pragma unroll
    for (int r = 0; r < 4; ++r) {
        const int row = r0 + wm * 16 + lg * 4 + r;
        outh[(size_t)row * KP + col] = (_Float16)(acc[r] + b1v);
    }
}

// ---------------------------------------------------------------------------
// Kernel 2: pairwise critic (r9-verified 4i x 4j x k-half core) + atomic
// row accumulation + last-block final reduction (atomics only, NO fences).
//   s[i][j] = sum_k relu(hy[i,k]+hx[j,k])*w2[k] + b2
//   partsum[i] += sum_{j in block} e^s   (exp(softplus) = 1+e^s identity)
//   diag[i]    = softplus(s[i][i])       (via atomicExch, coherent)
// Tile 32(i) x 64(j), 256 thr, 512 blocks. Block completion counted with a
// device-scope atomic after s_waitcnt vmcnt(0); block #512 reads partsum &
// diag back via atomic reads and produces out[0].
// ---------------------------------------------------------------------------
__global__ __launch_bounds__(256)
void pair_kernel(const unsigned int* __restrict__ hx_h, const unsigned int* __restrict__ hy_h,
                 const float* __restrict__ W2, const float* __restrict__ b2,
                 float* __restrict__ partsum, float* __restrict__ diag,
                 unsigned int* __restrict__ cnt, float* __restrict__ out)
{
    const int jb = blockIdx.x & 15, ib = blockIdx.x >> 4;
    const int j0 = jb * 64, i0 = ib * 32;

    __shared__ unsigned int Hy[160][36];   // [kk][i], 16B-aligned rows
    __shared__ unsigned int Hx[160][68];   // [kk][j]
    __shared__ unsigned int w2s[KP2];
    __shared__ unsigned int lastFlag;
    __shared__ float ssum[4];

    const int tid = threadIdx.x;

    // ---- stage Hy: transpose [i][kk] -> [kk][i] ----
    {
        const int r = tid >> 3, q = tid & 7;
        const unsigned int* src = &hy_h[(size_t)(i0 + r) * KP2];
        #pragma unroll
        for (int e = 0; e < 5; ++e) {
            const int k4 = q + 8 * e;
            uint4 v = *(const uint4*)&src[k4 * 4];
            Hy[k4*4+0][r] = v.x; Hy[k4*4+1][r] = v.y;
            Hy[k4*4+2][r] = v.z; Hy[k4*4+3][r] = v.w;
        }
    }
    // ---- stage Hx ----
    {
        const int r = tid >> 2, q = tid & 3;
        const unsigned int* src = &hx_h[(size_t)(j0 + r) * KP2];
        #pragma unroll
        for (int e = 0; e < 10; ++e) {
            const int k4 = q + 4 * e;
            uint4 v = *(const uint4*)&src[k4 * 4];
            Hx[k4*4+0][r] = v.x; Hx[k4*4+1][r] = v.y;
            Hx[k4*4+2][r] = v.z; Hx[k4*4+3][r] = v.w;
        }
    }
    if (tid < KP2) {
        int k = tid * 2;
        float w0 = (k < LOW) ? W2[k] : 0.f;
        float w1 = (k + 1 < LOW) ? W2[k + 1] : 0.f;
        w2s[tid] = pk(w0, w1);
    }
    __syncthreads();

    const int tx = tid & 15;           // j = j0 + tx*4 + q
    const int kh = (tid >> 4) & 1;     // k-half
    const int iy = tid >> 5;           // i = i0 + iy*4 + r

    float acc[4][4] = {};
    const h2 hz = h2{(_Float16)0.f, (_Float16)0.f};
    const int kbase = kh * 80;

    #pragma unroll 4
    for (int kki = 0; kki < 80; ++kki) {
        const int kk = kbase + kki;
        const uint4 ya = *(const uint4*)&Hy[kk][iy * 4];
        const uint4 xb = *(const uint4*)&Hx[kk][tx * 4];
        const h2 w = u2h(w2s[kk]);
        const unsigned int yar[4] = {ya.x, ya.y, ya.z, ya.w};
        const unsigned int xbr[4] = {xb.x, xb.y, xb.z, xb.w};
        #pragma unroll
        for (int r = 0; r < 4; ++r) {
            const h2 a = u2h(yar[r]);
            #pragma unroll
            for (int q = 0; q < 4; ++q) {
                h2 z = __builtin_elementwise_max(a + u2h(xbr[q]), hz);
                acc[r][q] = __builtin_amdgcn_fdot2(z, w, acc[r][q], false);
            }
        }
    }

    // combine the two k-halves (partner lane differs in bit 4)
    #pragma unroll
    for (int r = 0; r < 4; ++r)
        #pragma unroll
        for (int q = 0; q < 4; ++q)
            acc[r][q] += __shfl_xor(acc[r][q], 16, 64);

    const float b2v = b2[0];
    #pragma unroll
    for (int r = 0; r < 4; ++r) {
        const int row = i0 + iy * 4 + r;
        float es = 0.f;
        #pragma unroll
        for (int q = 0; q < 4; ++q) {
            const float s = acc[r][q] + b2v;
            es += __expf(s);
            const int col = j0 + tx * 4 + q;
            if (col == row)
                atomicExch(&diag[row],
                           fmaxf(s, 0.f) + __logf(1.f + __expf(-fabsf(s))));
        }
        #pragma unroll
        for (int o = 1; o <= 8; o <<= 1) es += __shfl_xor(es, o, 64);
        if ((tid & 31) == 0) atomicAdd(&partsum[row], es);
    }

    // ---- completion protocol: drain this wave's atomics, then count ----
    asm volatile("s_waitcnt vmcnt(0)" ::: "memory");
    __syncthreads();
    if (tid == 0) lastFlag = (atomicAdd(cnt, 1u) == 511u) ? 1u : 0u;
    __syncthreads();
    if (!lastFlag) return;

    // ---- final lse + mean (atomic reads: coherent, no fence needed) ----
    float csum = 0.f;
    #pragma unroll
    for (int g = 0; g < 4; ++g) {
        const int row = g * 256 + tid;
        const float ps = atomicAdd(&partsum[row], 0.f);   // coherent read
        const float dg = atomicAdd(&diag[row], 0.f);      // coherent read
        csum += dg - __logf((float)N_S + ps);
    }
    #pragma unroll
    for (int o = 32; o > 0; o >>= 1) csum += __shfl_xor(csum, o, 64);
    if ((tid & 63) == 0) ssum[tid >> 6] = csum;
    __syncthreads();
    if (tid == 0)
        out[0] = (ssum[0] + ssum[1] + ssum[2] + ssum[3]) * (1.0f / N_S)
               - logf((float)N_S);
}

// ---------------------------------------------------------------------------
extern "C" void kernel_launch(void* const* d_in, const int* in_sizes, int n_in,
                              void* d_out, int out_size, void* d_ws, size_t ws_size,
                              hipStream_t stream)
{
    const float* x  = (const float*)d_in[0];
    const float* y  = (const float*)d_in[1];
    const float* W1 = (const float*)d_in[2];
    const float* b1 = (const float*)d_in[3];
    const float* W2 = (const float*)d_in[4];
    const float* b2 = (const float*)d_in[5];
    float* outp = (float*)d_out;

    unsigned int* hx_h = (unsigned int*)d_ws;             // N_S*KP2 u32
    unsigned int* hy_h = hx_h + (size_t)N_S * KP2;        // N_S*KP2 u32
    float* partsum = (float*)(hy_h + (size_t)N_S * KP2);  // N_S f32
    float* diag = partsum + N_S;                          // N_S f32
    unsigned int* cnt = (unsigned int*)(diag + N_S);      // 1 u32

    gemm_h<<<320, 512, 0, stream>>>(x, y, W1, b1, hx_h, hy_h, partsum, cnt);

    pair_kernel<<<512, 256, 0, stream>>>(hx_h, hy_h, W2, b2,
                                         partsum, diag, cnt, outp);
}